// Round 1
// baseline (5532.842 us; speedup 1.0000x reference)
//
#include <hip/hip_runtime.h>
#include <math.h>

#define Bsz 32
#define Hd  512
#define SEQ 128
#define G4H 2048
#define BH  16384   // Bsz*Hd

// ---------------- weight pre-pack ----------------
// out[blk][ (k&15)*256 + (k>>4)*8 + jj ] = W[j][k],  j = (jj>>1)*512 + blk*2 + (jj&1)
// This is exactly the LDS layout lstm_step_k reads: per (kk,ks) row of 8 cols,
// so the wave's 8 distinct k-split addresses land on different bank quads.
__global__ __launch_bounds__(256) void pack_w_k(const float* __restrict__ W,
                                                float* __restrict__ out) {
  int o = blockIdx.x * 256 + threadIdx.x;          // 256*4096 total
  int blk = o >> 12, r = o & 4095;
  int kk = r >> 8, rest = r & 255, ks2 = rest >> 3, jj = rest & 7;
  int k = (ks2 << 4) + kk;
  int j = ((jj >> 1) << 9) + (blk << 1) + (jj & 1);
  out[o] = W[j * Hd + k];
}

__global__ __launch_bounds__(256) void bias_sum_k(const float* __restrict__ a,
                                                  const float* __restrict__ b,
                                                  float* __restrict__ out) {
  int i = blockIdx.x * 256 + threadIdx.x;
  if (i < G4H) out[i] = a[i] + b[i];
}

__global__ __launch_bounds__(256) void embed_k(const int* __restrict__ idx,
                                               const float* __restrict__ emb,
                                               float* __restrict__ out) {
  int t = blockIdx.x * 256 + threadIdx.x;          // ntok*64 threads (E=256 -> 64 f4)
  int m = t >> 6, e4 = (t & 63) << 2;
  *(float4*)&out[(size_t)m * 256 + e4] =
      *(const float4*)&emb[(size_t)idx[m] * 256 + e4];
}

// ---------------- fp32 NT GEMM: C[m][n] = sum_k A[m][k]*Wt[n][k] + bias[n] ----------------
// grid (N/64, M/64), 256 thr, 4x4 micro-tile, BK=32, transpose-on-store LDS (+4 pad).
__global__ __launch_bounds__(256, 2)
void gemm_nt_k(const float* __restrict__ A, const float* __restrict__ Wt,
               const float* __restrict__ bias, float* __restrict__ C,
               int K, int ldc)
{
  __shared__ float As[32 * 68];
  __shared__ float Ws[32 * 68];
  const int tid = threadIdx.x;
  const int m0 = blockIdx.y << 6, n0 = blockIdx.x << 6;
  const int tn = tid & 15, tm = tid >> 4;
  const int lr = tid >> 2, lk = (tid & 3) << 3;
  float acc[4][4] = {};
  for (int kt = 0; kt < K; kt += 32) {
    #pragma unroll
    for (int i = 0; i < 2; ++i) {
      float4 a = *(const float4*)&A[(size_t)(m0 + lr) * K + kt + lk + (i << 2)];
      float4 w = *(const float4*)&Wt[(size_t)(n0 + lr) * K + kt + lk + (i << 2)];
      const float* ap = (const float*)&a;
      const float* wp = (const float*)&w;
      #pragma unroll
      for (int d = 0; d < 4; ++d) {
        As[(lk + (i << 2) + d) * 68 + lr] = ap[d];
        Ws[(lk + (i << 2) + d) * 68 + lr] = wp[d];
      }
    }
    __syncthreads();
    #pragma unroll 8
    for (int kk = 0; kk < 32; ++kk) {
      float4 av = *(const float4*)&As[kk * 68 + (tm << 2)];
      float4 wv = *(const float4*)&Ws[kk * 68 + (tn << 2)];
      const float* ap = (const float*)&av;
      const float* wp = (const float*)&wv;
      #pragma unroll
      for (int i = 0; i < 4; ++i)
        #pragma unroll
        for (int j = 0; j < 4; ++j)
          acc[i][j] += ap[i] * wp[j];
    }
    __syncthreads();
  }
  #pragma unroll
  for (int i = 0; i < 4; ++i) {
    float4 o;
    float* op = (float*)&o;
    #pragma unroll
    for (int j = 0; j < 4; ++j) op[j] = acc[i][j] + bias[n0 + (tn << 2) + j];
    *(float4*)&C[(size_t)(m0 + (tm << 2) + i) * ldc + n0 + (tn << 2)] = o;
  }
}

// ---------------- fused LSTM super-step ----------------
// Super-step u: layer0 at t=u (if u<128) and layer1 at t=u-1 (if u>=1).
// h0 state after step t lives in h0buf[t&1]; h1 state after step t in h1buf[t&1].
// Block blk owns cells n0=2*blk,{+1} (all 4 gates, both layers), all 32 batch rows.
// Threads: bg=tid&7 (4 batch rows each), ks=tid>>3 (k-chunk of 16).
__global__ __launch_bounds__(256, 1)
void lstm_step_k(const float* __restrict__ w0p,  // packed Whh0  [256][4096]
                 const float* __restrict__ w1ap, // packed Wih1
                 const float* __restrict__ w1bp, // packed Whh1
                 const float* __restrict__ x0pre,// [B*SEQ][2048] input gates (+biases)
                 const float* __restrict__ bias1,// [2048] bih1+bhh1
                 float* __restrict__ h0buf, float* __restrict__ h1buf,
                 float* __restrict__ c0, float* __restrict__ c1,
                 float* __restrict__ dec_out,    // [B][SEQ][Hd] or nullptr
                 int u)
{
  __shared__ float w0s[4096], w1as[4096], w1bs[4096];
  __shared__ float rbuf[8192];
  __shared__ float gbuf[256];

  const int blk = blockIdx.x, tid = threadIdx.x;
  const int bg = tid & 7, ks = tid >> 3;
  const int n0 = blk << 1;
  const bool doL0 = (u < SEQ), doL1 = (u >= 1);
  const int pA = (u + 1) & 1;  // h0 READ parity (state u-1); h1 WRITE parity (state u-1)
  const int pW = u & 1;        // h0 WRITE parity (state u);  h1 READ parity (state u-2)

  // ---- h preloads into registers (each element read exactly once per block) ----
  float hA[4][16], hB[4][16];
  {
    const float* h0p = h0buf + pA * BH;
    #pragma unroll
    for (int bi = 0; bi < 4; ++bi) {
      int b = (bg << 2) + bi;
      #pragma unroll
      for (int q = 0; q < 4; ++q) {
        float4 t = *(const float4*)&h0p[b * Hd + (ks << 4) + (q << 2)];
        hA[bi][q * 4 + 0] = t.x; hA[bi][q * 4 + 1] = t.y;
        hA[bi][q * 4 + 2] = t.z; hA[bi][q * 4 + 3] = t.w;
      }
    }
  }
  if (doL1) {
    const float* h1p = h1buf + pW * BH;
    #pragma unroll
    for (int bi = 0; bi < 4; ++bi) {
      int b = (bg << 2) + bi;
      #pragma unroll
      for (int q = 0; q < 4; ++q) {
        float4 t = *(const float4*)&h1p[b * Hd + (ks << 4) + (q << 2)];
        hB[bi][q * 4 + 0] = t.x; hB[bi][q * 4 + 1] = t.y;
        hB[bi][q * 4 + 2] = t.z; hB[bi][q * 4 + 3] = t.w;
      }
    }
  }

  // ---- stage packed weights to LDS (linear copy) ----
  if (doL0)
    for (int i = tid * 4; i < 4096; i += 1024)
      *(float4*)&w0s[i] = *(const float4*)&w0p[((size_t)blk << 12) + i];
  if (doL1) {
    for (int i = tid * 4; i < 4096; i += 1024)
      *(float4*)&w1as[i] = *(const float4*)&w1ap[((size_t)blk << 12) + i];
    for (int i = tid * 4; i < 4096; i += 1024)
      *(float4*)&w1bs[i] = *(const float4*)&w1bp[((size_t)blk << 12) + i];
  }
  __syncthreads();

  __attribute__((aligned(16))) float acc0[8][4];
  __attribute__((aligned(16))) float acc1[8][4];
  #pragma unroll
  for (int jj = 0; jj < 8; ++jj)
    #pragma unroll
    for (int bi = 0; bi < 4; ++bi) { acc0[jj][bi] = 0.f; acc1[jj][bi] = 0.f; }

  const int wbase = ks << 3;
  if (doL0) {
    #pragma unroll
    for (int kk = 0; kk < 16; ++kk) {
      float4 wlo = *(const float4*)&w0s[(kk << 8) + wbase];
      float4 whi = *(const float4*)&w0s[(kk << 8) + wbase + 4];
      const float* wl = (const float*)&wlo;
      const float* wh = (const float*)&whi;
      #pragma unroll
      for (int jj = 0; jj < 4; ++jj)
        #pragma unroll
        for (int bi = 0; bi < 4; ++bi) {
          acc0[jj][bi]     += wl[jj] * hA[bi][kk];
          acc0[4 + jj][bi] += wh[jj] * hA[bi][kk];
        }
    }
  }
  if (doL1) {
    #pragma unroll
    for (int kk = 0; kk < 16; ++kk) {   // Wih1 . h0(u-1)
      float4 wlo = *(const float4*)&w1as[(kk << 8) + wbase];
      float4 whi = *(const float4*)&w1as[(kk << 8) + wbase + 4];
      const float* wl = (const float*)&wlo;
      const float* wh = (const float*)&whi;
      #pragma unroll
      for (int jj = 0; jj < 4; ++jj)
        #pragma unroll
        for (int bi = 0; bi < 4; ++bi) {
          acc1[jj][bi]     += wl[jj] * hA[bi][kk];
          acc1[4 + jj][bi] += wh[jj] * hA[bi][kk];
        }
    }
    #pragma unroll
    for (int kk = 0; kk < 16; ++kk) {   // Whh1 . h1(u-2)
      float4 wlo = *(const float4*)&w1bs[(kk << 8) + wbase];
      float4 whi = *(const float4*)&w1bs[(kk << 8) + wbase + 4];
      const float* wl = (const float*)&wlo;
      const float* wh = (const float*)&whi;
      #pragma unroll
      for (int jj = 0; jj < 4; ++jj)
        #pragma unroll
        for (int bi = 0; bi < 4; ++bi) {
          acc1[jj][bi]     += wl[jj] * hB[bi][kk];
          acc1[4 + jj][bi] += wh[jj] * hB[bi][kk];
        }
    }
  }

  // ---- layer0: k-split reduce -> gates -> pointwise ----
  if (doL0) {
    #pragma unroll
    for (int jj = 0; jj < 8; ++jj)
      *(float4*)&rbuf[(ks << 8) + (bg << 5) + ((jj ^ bg) << 2)] = *(const float4*)acc0[jj];
    __syncthreads();
    {
      int col = tid & 7, b = tid >> 3, bgr = b >> 2, bi = b & 3;
      float s = 0.f;
      #pragma unroll 8
      for (int k2 = 0; k2 < 32; ++k2)
        s += rbuf[(k2 << 8) + (bgr << 5) + ((col ^ bgr) << 2) + bi];
      int j = ((col >> 1) << 9) + n0 + (col & 1);
      s += x0pre[(size_t)(b * SEQ + u) * G4H + j];
      gbuf[(col << 5) + b] = s;
    }
    __syncthreads();
    if (tid < 64) {
      int cc = tid & 1, b2 = tid >> 1, n = n0 + cc;
      float gi = gbuf[((0 + cc) << 5) + b2];
      float gf = gbuf[((2 + cc) << 5) + b2];
      float gg = gbuf[((4 + cc) << 5) + b2];
      float go = gbuf[((6 + cc) << 5) + b2];
      float i_ = 1.f / (1.f + expf(-gi));
      float f_ = 1.f / (1.f + expf(-gf));
      float o_ = 1.f / (1.f + expf(-go));
      float g_ = tanhf(gg);
      float cold = c0[b2 * Hd + n];
      float cn = f_ * cold + i_ * g_;
      float hn = o_ * tanhf(cn);
      c0[b2 * Hd + n] = cn;
      h0buf[pW * BH + b2 * Hd + n] = hn;
    }
    __syncthreads();
  }

  // ---- layer1: reduce -> gates -> pointwise ----
  if (doL1) {
    #pragma unroll
    for (int jj = 0; jj < 8; ++jj)
      *(float4*)&rbuf[(ks << 8) + (bg << 5) + ((jj ^ bg) << 2)] = *(const float4*)acc1[jj];
    __syncthreads();
    {
      int col = tid & 7, b = tid >> 3, bgr = b >> 2, bi = b & 3;
      float s = 0.f;
      #pragma unroll 8
      for (int k2 = 0; k2 < 32; ++k2)
        s += rbuf[(k2 << 8) + (bgr << 5) + ((col ^ bgr) << 2) + bi];
      int j = ((col >> 1) << 9) + n0 + (col & 1);
      s += bias1[j];
      gbuf[(col << 5) + b] = s;
    }
    __syncthreads();
    if (tid < 64) {
      int cc = tid & 1, b2 = tid >> 1, n = n0 + cc, t = u - 1;
      float gi = gbuf[((0 + cc) << 5) + b2];
      float gf = gbuf[((2 + cc) << 5) + b2];
      float gg = gbuf[((4 + cc) << 5) + b2];
      float go = gbuf[((6 + cc) << 5) + b2];
      float i_ = 1.f / (1.f + expf(-gi));
      float f_ = 1.f / (1.f + expf(-gf));
      float o_ = 1.f / (1.f + expf(-go));
      float g_ = tanhf(gg);
      float cold = c1[b2 * Hd + n];
      float cn = f_ * cold + i_ * g_;
      float hn = o_ * tanhf(cn);
      c1[b2 * Hd + n] = cn;
      h1buf[pA * BH + b2 * Hd + n] = hn;
      if (dec_out) dec_out[((size_t)b2 * SEQ + t) * Hd + n] = hn;
    }
  }
}

// ---------------- host ----------------
extern "C" void kernel_launch(void* const* d_in, const int* in_sizes, int n_in,
                              void* d_out, int out_size, void* d_ws, size_t ws_size,
                              hipStream_t stream) {
  const int*   src  = (const int*)d_in[0];
  const int*   tgt  = (const int*)d_in[1];
  const float* emb  = (const float*)d_in[2];
  const float* Wout = (const float*)d_in[3];
  const float* bout = (const float*)d_in[4];
  const float* eWih0 = (const float*)d_in[5];
  const float* eWhh0 = (const float*)d_in[6];
  const float* ebih0 = (const float*)d_in[7];
  const float* ebhh0 = (const float*)d_in[8];
  const float* eWih1 = (const float*)d_in[9];
  const float* eWhh1 = (const float*)d_in[10];
  const float* ebih1 = (const float*)d_in[11];
  const float* ebhh1 = (const float*)d_in[12];
  const float* dWih0 = (const float*)d_in[13];
  const float* dWhh0 = (const float*)d_in[14];
  const float* dbih0 = (const float*)d_in[15];
  const float* dbhh0 = (const float*)d_in[16];
  const float* dWih1 = (const float*)d_in[17];
  const float* dWhh1 = (const float*)d_in[18];
  const float* dbih1 = (const float*)d_in[19];
  const float* dbhh1 = (const float*)d_in[20];

  float* ws = (float*)d_ws;
  const size_t OFF_EMB  = 0;         // 4096*256
  const size_t OFF_X0   = 1048576;   // 4096*2048 (reused enc then dec)
  const size_t OFF_W0E  = 9437184;
  const size_t OFF_W1AE = 10485760;
  const size_t OFF_W1BE = 11534336;
  const size_t OFF_W0D  = 12582912;
  const size_t OFF_W1AD = 13631488;
  const size_t OFF_W1BD = 14680064;
  const size_t OFF_BS0E = 15728640;
  const size_t OFF_B1E  = 15730688;
  const size_t OFF_BS0D = 15732736;
  const size_t OFF_B1D  = 15734784;
  const size_t OFF_H0   = 15736832;  // 2*BH
  const size_t OFF_H1   = 15769600;  // 2*BH
  const size_t OFF_C0   = 15802368;  // BH
  const size_t OFF_C1   = 15818752;  // BH
  const size_t OFF_DOUT = 15835136;  // 4096*512

  // pack weights + bias sums
  pack_w_k<<<4096, 256, 0, stream>>>(eWhh0, ws + OFF_W0E);
  pack_w_k<<<4096, 256, 0, stream>>>(eWih1, ws + OFF_W1AE);
  pack_w_k<<<4096, 256, 0, stream>>>(eWhh1, ws + OFF_W1BE);
  pack_w_k<<<4096, 256, 0, stream>>>(dWhh0, ws + OFF_W0D);
  pack_w_k<<<4096, 256, 0, stream>>>(dWih1, ws + OFF_W1AD);
  pack_w_k<<<4096, 256, 0, stream>>>(dWhh1, ws + OFF_W1BD);
  bias_sum_k<<<8, 256, 0, stream>>>(ebih0, ebhh0, ws + OFF_BS0E);
  bias_sum_k<<<8, 256, 0, stream>>>(ebih1, ebhh1, ws + OFF_B1E);
  bias_sum_k<<<8, 256, 0, stream>>>(dbih0, dbhh0, ws + OFF_BS0D);
  bias_sum_k<<<8, 256, 0, stream>>>(dbih1, dbhh1, ws + OFF_B1D);

  // zero LSTM state (h0/h1 ping-pong + c0/c1)
  hipMemsetAsync(ws + OFF_H0, 0, (size_t)(2 * BH + 2 * BH + BH + BH) * 4, stream);

  // encoder: embed -> input gates GEMM -> 129 super-steps
  embed_k<<<1024, 256, 0, stream>>>(src, emb, ws + OFF_EMB);
  gemm_nt_k<<<dim3(32, 64), 256, 0, stream>>>(ws + OFF_EMB, eWih0, ws + OFF_BS0E,
                                              ws + OFF_X0, 256, 2048);
  for (int u = 0; u <= SEQ; ++u)
    lstm_step_k<<<256, 256, 0, stream>>>(ws + OFF_W0E, ws + OFF_W1AE, ws + OFF_W1BE,
                                         ws + OFF_X0, ws + OFF_B1E,
                                         ws + OFF_H0, ws + OFF_H1, ws + OFF_C0, ws + OFF_C1,
                                         nullptr, u);

  // decoder: embed -> input gates GEMM -> 129 super-steps (state continues)
  embed_k<<<1024, 256, 0, stream>>>(tgt, emb, ws + OFF_EMB);
  gemm_nt_k<<<dim3(32, 64), 256, 0, stream>>>(ws + OFF_EMB, dWih0, ws + OFF_BS0D,
                                              ws + OFF_X0, 256, 2048);
  for (int u = 0; u <= SEQ; ++u)
    lstm_step_k<<<256, 256, 0, stream>>>(ws + OFF_W0D, ws + OFF_W1AD, ws + OFF_W1BD,
                                         ws + OFF_X0, ws + OFF_B1D,
                                         ws + OFF_H0, ws + OFF_H1, ws + OFF_C0, ws + OFF_C1,
                                         ws + OFF_DOUT, u);

  // vocab projection: logits = dec_out @ Wout^T + bout
  gemm_nt_k<<<dim3(500, 64), 256, 0, stream>>>(ws + OFF_DOUT, Wout, bout,
                                               (float*)d_out, 512, 32000);
}

// Round 2
// 4150.595 us; speedup vs baseline: 1.3330x; 1.3330x over previous
//
#include <hip/hip_runtime.h>
#include <math.h>

#define Bsz 32
#define Hd  512
#define SEQ 128
#define G4H 2048
#define BH  16384   // Bsz*Hd

typedef __attribute__((ext_vector_type(8))) short bf16x8;
typedef __attribute__((ext_vector_type(4))) float f32x4;
typedef __attribute__((ext_vector_type(4))) unsigned short us4;

__device__ __forceinline__ void gload16(const void* g, void* l) {
  __builtin_amdgcn_global_load_lds(
      (const __attribute__((address_space(1))) unsigned int*)g,
      (__attribute__((address_space(3))) unsigned int*)l, 16, 0, 0);
}

// ---------------- weight pre-pack (coalesced via LDS) ----------------
// out[blk*4096 + i], i = kk*256 + ks2*8 + jj  <->  W[j][k], j=(jj>>1)*512+blk*2+(jj&1), k=ks2*16+kk
__global__ __launch_bounds__(256) void pack_w_k(const float* __restrict__ W,
                                                float* __restrict__ out) {
  __shared__ float Wl[8][512];
  const int blk = blockIdx.x, tid = threadIdx.x;
  #pragma unroll
  for (int r = 0; r < 8; ++r) {
    int j = ((r >> 1) << 9) + (blk << 1) + (r & 1);
    Wl[r][tid] = W[j * Hd + tid];
    Wl[r][tid + 256] = W[j * Hd + tid + 256];
  }
  __syncthreads();
  #pragma unroll
  for (int q = 0; q < 16; ++q) {
    int i = tid * 16 + q;
    int kk = i >> 8, rest = i & 255, ks2 = rest >> 3, jj = rest & 7;
    out[((size_t)blk << 12) + i] = Wl[jj][(ks2 << 4) + kk];
  }
}

__global__ __launch_bounds__(256) void bias_sum_k(const float* __restrict__ a,
                                                  const float* __restrict__ b,
                                                  float* __restrict__ out) {
  int i = blockIdx.x * 256 + threadIdx.x;
  if (i < G4H) out[i] = a[i] + b[i];
}

__global__ __launch_bounds__(256) void embed_k(const int* __restrict__ idx,
                                               const float* __restrict__ emb,
                                               float* __restrict__ out) {
  int t = blockIdx.x * 256 + threadIdx.x;          // ntok*64 threads (E=256 -> 64 f4)
  int m = t >> 6, e4 = (t & 63) << 2;
  *(float4*)&out[(size_t)m * 256 + e4] =
      *(const float4*)&emb[(size_t)idx[m] * 256 + e4];
}

// ---------------- fp32 -> bf16 hi/lo split ----------------
__global__ __launch_bounds__(256) void split_k(const float* __restrict__ X,
                                               unsigned short* __restrict__ hi,
                                               unsigned short* __restrict__ lo) {
  int i = (blockIdx.x * 256 + threadIdx.x) << 2;
  float4 x = *(const float4*)&X[i];
  const float* xp = (const float*)&x;
  us4 h, l;
  #pragma unroll
  for (int e = 0; e < 4; ++e) {
    float v = xp[e];
    unsigned int u = __float_as_uint(v);
    unsigned int hr = (u + 0x7fffu + ((u >> 16) & 1u)) & 0xffff0000u;
    h[e] = (unsigned short)(hr >> 16);
    float rem = v - __uint_as_float(hr);
    unsigned int u2 = __float_as_uint(rem);
    l[e] = (unsigned short)((u2 + 0x7fffu + ((u2 >> 16) & 1u)) >> 16);
  }
  *(us4*)&hi[i] = h;
  *(us4*)&lo[i] = l;
}

// ---------------- fp32 NT GEMM (input gates + fallback) ----------------
__global__ __launch_bounds__(256, 2)
void gemm_nt_k(const float* __restrict__ A, const float* __restrict__ Wt,
               const float* __restrict__ bias, float* __restrict__ C,
               int K, int ldc)
{
  __shared__ float As[32 * 68];
  __shared__ float Ws[32 * 68];
  const int tid = threadIdx.x;
  const int m0 = blockIdx.y << 6, n0 = blockIdx.x << 6;
  const int tn = tid & 15, tm = tid >> 4;
  const int lr = tid >> 2, lk = (tid & 3) << 3;
  float acc[4][4] = {};
  for (int kt = 0; kt < K; kt += 32) {
    #pragma unroll
    for (int i = 0; i < 2; ++i) {
      float4 a = *(const float4*)&A[(size_t)(m0 + lr) * K + kt + lk + (i << 2)];
      float4 w = *(const float4*)&Wt[(size_t)(n0 + lr) * K + kt + lk + (i << 2)];
      const float* ap = (const float*)&a;
      const float* wp = (const float*)&w;
      #pragma unroll
      for (int d = 0; d < 4; ++d) {
        As[(lk + (i << 2) + d) * 68 + lr] = ap[d];
        Ws[(lk + (i << 2) + d) * 68 + lr] = wp[d];
      }
    }
    __syncthreads();
    #pragma unroll 8
    for (int kk = 0; kk < 32; ++kk) {
      float4 av = *(const float4*)&As[kk * 68 + (tm << 2)];
      float4 wv = *(const float4*)&Ws[kk * 68 + (tn << 2)];
      const float* ap = (const float*)&av;
      const float* wp = (const float*)&wv;
      #pragma unroll
      for (int i = 0; i < 4; ++i)
        #pragma unroll
        for (int j = 0; j < 4; ++j)
          acc[i][j] += ap[i] * wp[j];
    }
    __syncthreads();
  }
  #pragma unroll
  for (int i = 0; i < 4; ++i) {
    float4 o;
    float* op = (float*)&o;
    #pragma unroll
    for (int j = 0; j < 4; ++j) op[j] = acc[i][j] + bias[n0 + (tn << 2) + j];
    *(float4*)&C[(size_t)(m0 + (tm << 2) + i) * ldc + n0 + (tn << 2)] = o;
  }
}

// ---------------- bf16 MFMA 3-term split projection ----------------
// C[m][n] = sum_seg sum_k A[m][k]*B[n][k] + bias[n]; 128x128 tile, 4 waves 64x64 each,
// BK=32, global_load_lds width16, mfma_f32_16x16x32_bf16 (m89 C/D layout).
__global__ __launch_bounds__(256)
void gemm_bf16_split_k(const unsigned short* __restrict__ Ahi,
                       const unsigned short* __restrict__ Alo,
                       const unsigned short* __restrict__ Bhi,
                       const unsigned short* __restrict__ Blo,
                       const float* __restrict__ bias,
                       float* __restrict__ C)
{
  __shared__ unsigned short As[4096];   // [128][32]
  __shared__ unsigned short Bs[4096];   // [128][32]
  const int tid = threadIdx.x;
  const int m0 = blockIdx.x << 7, n0 = blockIdx.y << 7;
  const int lane = tid & 63, wave = tid >> 6;
  const int wr = wave >> 1, wc = wave & 1;
  const int srow = wave * 32 + (lane >> 2);   // staging row (+16 for 2nd chunk)
  const int sk = (lane & 3) << 3;             // staging k offset (halfwords)
  const int ldse = wave * 1024 + lane * 8;    // staging LDS halfword index
  const int fr = lane & 15, fk = (lane >> 4) << 3;

  f32x4 acc[4][4];
  #pragma unroll
  for (int a = 0; a < 4; ++a)
    #pragma unroll
    for (int b = 0; b < 4; ++b) acc[a][b] = (f32x4){0.f, 0.f, 0.f, 0.f};

  #pragma unroll 1
  for (int seg = 0; seg < 3; ++seg) {
    const unsigned short* Ab = (seg == 2) ? Alo : Ahi;
    const unsigned short* Bb = (seg == 1) ? Blo : Bhi;
    #pragma unroll 1
    for (int kt = 0; kt < 512; kt += 32) {
      gload16(Ab + (size_t)(m0 + srow) * 512 + kt + sk, &As[ldse]);
      gload16(Ab + (size_t)(m0 + srow + 16) * 512 + kt + sk, &As[ldse + 512]);
      gload16(Bb + (size_t)(n0 + srow) * 512 + kt + sk, &Bs[ldse]);
      gload16(Bb + (size_t)(n0 + srow + 16) * 512 + kt + sk, &Bs[ldse + 512]);
      __syncthreads();   // drains vmcnt (global_load_lds) + barrier
      bf16x8 af[4], bf[4];
      #pragma unroll
      for (int mf = 0; mf < 4; ++mf)
        af[mf] = *(const bf16x8*)&As[(wr * 64 + mf * 16 + fr) * 32 + fk];
      #pragma unroll
      for (int nf = 0; nf < 4; ++nf)
        bf[nf] = *(const bf16x8*)&Bs[(wc * 64 + nf * 16 + fr) * 32 + fk];
      #pragma unroll
      for (int mf = 0; mf < 4; ++mf)
        #pragma unroll
        for (int nf = 0; nf < 4; ++nf)
          acc[mf][nf] = __builtin_amdgcn_mfma_f32_16x16x32_bf16(af[mf], bf[nf],
                                                                acc[mf][nf], 0, 0, 0);
      __syncthreads();   // protect LDS before next stage
    }
  }

  const int rgrp = (lane >> 4) << 2;
  #pragma unroll
  for (int nf = 0; nf < 4; ++nf) {
    int n = n0 + wc * 64 + nf * 16 + fr;
    float bn = bias[n];
    #pragma unroll
    for (int mf = 0; mf < 4; ++mf) {
      #pragma unroll
      for (int r = 0; r < 4; ++r) {
        int m = m0 + wr * 64 + mf * 16 + rgrp + r;
        C[(size_t)m * 32000 + n] = acc[mf][nf][r] + bn;
      }
    }
  }
}

// ---------------- fused LSTM super-step (unchanged) ----------------
__global__ __launch_bounds__(256, 1)
void lstm_step_k(const float* __restrict__ w0p,  // packed Whh0  [256][4096]
                 const float* __restrict__ w1ap, // packed Wih1
                 const float* __restrict__ w1bp, // packed Whh1
                 const float* __restrict__ x0pre,// [B*SEQ][2048] input gates (+biases)
                 const float* __restrict__ bias1,// [2048] bih1+bhh1
                 float* __restrict__ h0buf, float* __restrict__ h1buf,
                 float* __restrict__ c0, float* __restrict__ c1,
                 float* __restrict__ dec_out,    // [B][SEQ][Hd] or nullptr
                 int u)
{
  __shared__ float w0s[4096], w1as[4096], w1bs[4096];
  __shared__ float rbuf[8192];
  __shared__ float gbuf[256];

  const int blk = blockIdx.x, tid = threadIdx.x;
  const int bg = tid & 7, ks = tid >> 3;
  const int n0 = blk << 1;
  const bool doL0 = (u < SEQ), doL1 = (u >= 1);
  const int pA = (u + 1) & 1;
  const int pW = u & 1;

  float hA[4][16], hB[4][16];
  {
    const float* h0p = h0buf + pA * BH;
    #pragma unroll
    for (int bi = 0; bi < 4; ++bi) {
      int b = (bg << 2) + bi;
      #pragma unroll
      for (int q = 0; q < 4; ++q) {
        float4 t = *(const float4*)&h0p[b * Hd + (ks << 4) + (q << 2)];
        hA[bi][q * 4 + 0] = t.x; hA[bi][q * 4 + 1] = t.y;
        hA[bi][q * 4 + 2] = t.z; hA[bi][q * 4 + 3] = t.w;
      }
    }
  }
  if (doL1) {
    const float* h1p = h1buf + pW * BH;
    #pragma unroll
    for (int bi = 0; bi < 4; ++bi) {
      int b = (bg << 2) + bi;
      #pragma unroll
      for (int q = 0; q < 4; ++q) {
        float4 t = *(const float4*)&h1p[b * Hd + (ks << 4) + (q << 2)];
        hB[bi][q * 4 + 0] = t.x; hB[bi][q * 4 + 1] = t.y;
        hB[bi][q * 4 + 2] = t.z; hB[bi][q * 4 + 3] = t.w;
      }
    }
  }

  if (doL0)
    for (int i = tid * 4; i < 4096; i += 1024)
      *(float4*)&w0s[i] = *(const float4*)&w0p[((size_t)blk << 12) + i];
  if (doL1) {
    for (int i = tid * 4; i < 4096; i += 1024)
      *(float4*)&w1as[i] = *(const float4*)&w1ap[((size_t)blk << 12) + i];
    for (int i = tid * 4; i < 4096; i += 1024)
      *(float4*)&w1bs[i] = *(const float4*)&w1bp[((size_t)blk << 12) + i];
  }
  __syncthreads();

  __attribute__((aligned(16))) float acc0[8][4];
  __attribute__((aligned(16))) float acc1[8][4];
  #pragma unroll
  for (int jj = 0; jj < 8; ++jj)
    #pragma unroll
    for (int bi = 0; bi < 4; ++bi) { acc0[jj][bi] = 0.f; acc1[jj][bi] = 0.f; }

  const int wbase = ks << 3;
  if (doL0) {
    #pragma unroll
    for (int kk = 0; kk < 16; ++kk) {
      float4 wlo = *(const float4*)&w0s[(kk << 8) + wbase];
      float4 whi = *(const float4*)&w0s[(kk << 8) + wbase + 4];
      const float* wl = (const float*)&wlo;
      const float* wh = (const float*)&whi;
      #pragma unroll
      for (int jj = 0; jj < 4; ++jj)
        #pragma unroll
        for (int bi = 0; bi < 4; ++bi) {
          acc0[jj][bi]     += wl[jj] * hA[bi][kk];
          acc0[4 + jj][bi] += wh[jj] * hA[bi][kk];
        }
    }
  }
  if (doL1) {
    #pragma unroll
    for (int kk = 0; kk < 16; ++kk) {
      float4 wlo = *(const float4*)&w1as[(kk << 8) + wbase];
      float4 whi = *(const float4*)&w1as[(kk << 8) + wbase + 4];
      const float* wl = (const float*)&wlo;
      const float* wh = (const float*)&whi;
      #pragma unroll
      for (int jj = 0; jj < 4; ++jj)
        #pragma unroll
        for (int bi = 0; bi < 4; ++bi) {
          acc1[jj][bi]     += wl[jj] * hA[bi][kk];
          acc1[4 + jj][bi] += wh[jj] * hA[bi][kk];
        }
    }
    #pragma unroll
    for (int kk = 0; kk < 16; ++kk) {
      float4 wlo = *(const float4*)&w1bs[(kk << 8) + wbase];
      float4 whi = *(const float4*)&w1bs[(kk << 8) + wbase + 4];
      const float* wl = (const float*)&wlo;
      const float* wh = (const float*)&whi;
      #pragma unroll
      for (int jj = 0; jj < 4; ++jj)
        #pragma unroll
        for (int bi = 0; bi < 4; ++bi) {
          acc1[jj][bi]     += wl[jj] * hB[bi][kk];
          acc1[4 + jj][bi] += wh[jj] * hB[bi][kk];
        }
    }
  }

  if (doL0) {
    #pragma unroll
    for (int jj = 0; jj < 8; ++jj)
      *(float4*)&rbuf[(ks << 8) + (bg << 5) + ((jj ^ bg) << 2)] = *(const float4*)acc0[jj];
    __syncthreads();
    {
      int col = tid & 7, b = tid >> 3, bgr = b >> 2, bi = b & 3;
      float s = 0.f;
      #pragma unroll 8
      for (int k2 = 0; k2 < 32; ++k2)
        s += rbuf[(k2 << 8) + (bgr << 5) + ((col ^ bgr) << 2) + bi];
      int j = ((col >> 1) << 9) + n0 + (col & 1);
      s += x0pre[(size_t)(b * SEQ + u) * G4H + j];
      gbuf[(col << 5) + b] = s;
    }
    __syncthreads();
    if (tid < 64) {
      int cc = tid & 1, b2 = tid >> 1, n = n0 + cc;
      float gi = gbuf[((0 + cc) << 5) + b2];
      float gf = gbuf[((2 + cc) << 5) + b2];
      float gg = gbuf[((4 + cc) << 5) + b2];
      float go = gbuf[((6 + cc) << 5) + b2];
      float i_ = 1.f / (1.f + expf(-gi));
      float f_ = 1.f / (1.f + expf(-gf));
      float o_ = 1.f / (1.f + expf(-go));
      float g_ = tanhf(gg);
      float cold = c0[b2 * Hd + n];
      float cn = f_ * cold + i_ * g_;
      float hn = o_ * tanhf(cn);
      c0[b2 * Hd + n] = cn;
      h0buf[pW * BH + b2 * Hd + n] = hn;
    }
    __syncthreads();
  }

  if (doL1) {
    #pragma unroll
    for (int jj = 0; jj < 8; ++jj)
      *(float4*)&rbuf[(ks << 8) + (bg << 5) + ((jj ^ bg) << 2)] = *(const float4*)acc1[jj];
    __syncthreads();
    {
      int col = tid & 7, b = tid >> 3, bgr = b >> 2, bi = b & 3;
      float s = 0.f;
      #pragma unroll 8
      for (int k2 = 0; k2 < 32; ++k2)
        s += rbuf[(k2 << 8) + (bgr << 5) + ((col ^ bgr) << 2) + bi];
      int j = ((col >> 1) << 9) + n0 + (col & 1);
      s += bias1[j];
      gbuf[(col << 5) + b] = s;
    }
    __syncthreads();
    if (tid < 64) {
      int cc = tid & 1, b2 = tid >> 1, n = n0 + cc, t = u - 1;
      float gi = gbuf[((0 + cc) << 5) + b2];
      float gf = gbuf[((2 + cc) << 5) + b2];
      float gg = gbuf[((4 + cc) << 5) + b2];
      float go = gbuf[((6 + cc) << 5) + b2];
      float i_ = 1.f / (1.f + expf(-gi));
      float f_ = 1.f / (1.f + expf(-gf));
      float o_ = 1.f / (1.f + expf(-go));
      float g_ = tanhf(gg);
      float cold = c1[b2 * Hd + n];
      float cn = f_ * cold + i_ * g_;
      float hn = o_ * tanhf(cn);
      c1[b2 * Hd + n] = cn;
      h1buf[pA * BH + b2 * Hd + n] = hn;
      if (dec_out) dec_out[((size_t)b2 * SEQ + t) * Hd + n] = hn;
    }
  }
}

// ---------------- host ----------------
extern "C" void kernel_launch(void* const* d_in, const int* in_sizes, int n_in,
                              void* d_out, int out_size, void* d_ws, size_t ws_size,
                              hipStream_t stream) {
  const int*   src  = (const int*)d_in[0];
  const int*   tgt  = (const int*)d_in[1];
  const float* emb  = (const float*)d_in[2];
  const float* Wout = (const float*)d_in[3];
  const float* bout = (const float*)d_in[4];
  const float* eWih0 = (const float*)d_in[5];
  const float* eWhh0 = (const float*)d_in[6];
  const float* ebih0 = (const float*)d_in[7];
  const float* ebhh0 = (const float*)d_in[8];
  const float* eWih1 = (const float*)d_in[9];
  const float* eWhh1 = (const float*)d_in[10];
  const float* ebih1 = (const float*)d_in[11];
  const float* ebhh1 = (const float*)d_in[12];
  const float* dWih0 = (const float*)d_in[13];
  const float* dWhh0 = (const float*)d_in[14];
  const float* dbih0 = (const float*)d_in[15];
  const float* dbhh0 = (const float*)d_in[16];
  const float* dWih1 = (const float*)d_in[17];
  const float* dWhh1 = (const float*)d_in[18];
  const float* dbih1 = (const float*)d_in[19];
  const float* dbhh1 = (const float*)d_in[20];

  float* ws = (float*)d_ws;
  char*  wsb = (char*)d_ws;
  const size_t OFF_EMB  = 0;         // 4096*256 f32
  const size_t OFF_X0   = 1048576;   // 4096*2048 f32 (reused enc then dec)
  const size_t OFF_W0E  = 9437184;
  const size_t OFF_W1AE = 10485760;
  const size_t OFF_W1BE = 11534336;
  const size_t OFF_W0D  = 12582912;
  const size_t OFF_W1AD = 13631488;
  const size_t OFF_W1BD = 14680064;
  const size_t OFF_BS0E = 15728640;
  const size_t OFF_B1E  = 15730688;
  const size_t OFF_BS0D = 15732736;
  const size_t OFF_B1D  = 15734784;
  const size_t OFF_H0   = 15736832;  // 2*BH
  const size_t OFF_H1   = 15769600;  // 2*BH
  const size_t OFF_C0   = 15802368;  // BH
  const size_t OFF_C1   = 15818752;  // BH
  const size_t OFF_DOUT = 15835136;  // 4096*512 f32 -> byte end 71,729,152
  // bf16 buffers (byte offsets)
  unsigned short* Bhi = (unsigned short*)(wsb + 71729152);   // 32000*512
  unsigned short* Blo = (unsigned short*)(wsb + 104497152);  // 32000*512
  unsigned short* Ahi = (unsigned short*)(wsb + 137265152);  // 4096*512
  unsigned short* Alo = (unsigned short*)(wsb + 141459456);  // 4096*512
  const bool use_mfma = ws_size >= 145653760ull;

  // split Wout into bf16 hi/lo (for MFMA projection)
  if (use_mfma)
    split_k<<<16000, 256, 0, stream>>>(Wout, Bhi, Blo);

  // pack weights + bias sums
  pack_w_k<<<256, 256, 0, stream>>>(eWhh0, ws + OFF_W0E);
  pack_w_k<<<256, 256, 0, stream>>>(eWih1, ws + OFF_W1AE);
  pack_w_k<<<256, 256, 0, stream>>>(eWhh1, ws + OFF_W1BE);
  pack_w_k<<<256, 256, 0, stream>>>(dWhh0, ws + OFF_W0D);
  pack_w_k<<<256, 256, 0, stream>>>(dWih1, ws + OFF_W1AD);
  pack_w_k<<<256, 256, 0, stream>>>(dWhh1, ws + OFF_W1BD);
  bias_sum_k<<<8, 256, 0, stream>>>(ebih0, ebhh0, ws + OFF_BS0E);
  bias_sum_k<<<8, 256, 0, stream>>>(ebih1, ebhh1, ws + OFF_B1E);
  bias_sum_k<<<8, 256, 0, stream>>>(dbih0, dbhh0, ws + OFF_BS0D);
  bias_sum_k<<<8, 256, 0, stream>>>(dbih1, dbhh1, ws + OFF_B1D);

  // zero LSTM state
  hipMemsetAsync(ws + OFF_H0, 0, (size_t)(2 * BH + 2 * BH + BH + BH) * 4, stream);

  // encoder
  embed_k<<<1024, 256, 0, stream>>>(src, emb, ws + OFF_EMB);
  gemm_nt_k<<<dim3(32, 64), 256, 0, stream>>>(ws + OFF_EMB, eWih0, ws + OFF_BS0E,
                                              ws + OFF_X0, 256, 2048);
  for (int u = 0; u <= SEQ; ++u)
    lstm_step_k<<<256, 256, 0, stream>>>(ws + OFF_W0E, ws + OFF_W1AE, ws + OFF_W1BE,
                                         ws + OFF_X0, ws + OFF_B1E,
                                         ws + OFF_H0, ws + OFF_H1, ws + OFF_C0, ws + OFF_C1,
                                         nullptr, u);

  // decoder
  embed_k<<<1024, 256, 0, stream>>>(tgt, emb, ws + OFF_EMB);
  gemm_nt_k<<<dim3(32, 64), 256, 0, stream>>>(ws + OFF_EMB, dWih0, ws + OFF_BS0D,
                                              ws + OFF_X0, 256, 2048);
  for (int u = 0; u <= SEQ; ++u)
    lstm_step_k<<<256, 256, 0, stream>>>(ws + OFF_W0D, ws + OFF_W1AD, ws + OFF_W1BD,
                                         ws + OFF_X0, ws + OFF_B1D,
                                         ws + OFF_H0, ws + OFF_H1, ws + OFF_C0, ws + OFF_C1,
                                         ws + OFF_DOUT, u);

  // vocab projection
  if (use_mfma) {
    split_k<<<2048, 256, 0, stream>>>(ws + OFF_DOUT, Ahi, Alo);
    gemm_bf16_split_k<<<dim3(32, 250), 256, 0, stream>>>(Ahi, Alo, Bhi, Blo,
                                                         bout, (float*)d_out);
  } else {
    gemm_nt_k<<<dim3(500, 64), 256, 0, stream>>>(ws + OFF_DOUT, Wout, bout,
                                                 (float*)d_out, 512, 32000);
  }
}